// Round 1
// 774.201 us; speedup vs baseline: 1.0447x; 1.0447x over previous
//
#include <hip/hip_runtime.h>
#include <math.h>

// Problem constants (match reference)
namespace {
constexpr int Bn    = 2048;
constexpr int CELLn = 512;
constexpr int Kn    = 30;   // alpha/beta/kappa each [B,30]
constexpr int Ln    = 1024; // padded text len
constexpr int Vn    = 80;   // vocab
constexpr int NT    = 256;  // 4 waves: 8 blocks/CU = 32 waves = full residency
constexpr int RP    = 12;   // row phases in the stream (12 x 20 = 240 lanes)
}

typedef float f4v __attribute__((ext_vector_type(4)));

// Fully fused: params GEMV -> phi -> per-row effective length -> sparse w stream.
//
// Key algorithmic fact: phi[b,l] = sum_k alpha_k exp(-beta_k (kappa_k - l)^2)
// underflows to EXACTLY 0.0f for l beyond ~kappa_max + sqrt(103/beta_min)
// (typically l ~ 30..90 of 1024). Terms with phi[b,l]==0.0f contribute
// exactly nothing to w — bit-identical to the dense sum over our own phi —
// so we stream only onehot rows l < n_eff(b), cutting the dominant HBM read
// from 671 MB to ~tens of MB. Worst case degrades gracefully to full stream.
//
// This revision targets per-block latency (the measurement is dominated by
// ~780 us of harness poison-fill; kernel residue is latency-bound):
//  - NT=256: full 32-wave/CU residency in one block generation (was 6/8).
//  - GEMV split across lane pairs (halves the serial dot chain), combined
//    with one __shfl_xor.
//  - phi computed 4 l-values per thread per k: 1/4 the s_abk LDS reads,
//    4-wide ILP on the dependent expf chains, one atomicMax per thread.
__global__ __launch_bounds__(NT, 8) void window_fused(
    const float* __restrict__ x,          // [B, CELL]
    const float* __restrict__ kappa_old,  // [B, K]
    const float* __restrict__ onehots,    // [B, L, V]
    const float* __restrict__ text_lens,  // [B, 1]
    const float* __restrict__ W,          // [3K, CELL]
    const float* __restrict__ bias,       // [3K]
    float* __restrict__ out_w,            // [B, V]
    float* __restrict__ out_kappa,        // [B, K]
    float* __restrict__ out_phi)          // [B, L+1]
{
    const int b = blockIdx.x;
    const int t = threadIdx.x;

    __shared__ float s_x[CELLn];       // 2 KB
    __shared__ float s_abk[3 * Kn];    // alpha[0:30], beta[30:60], kappa[60:90]
    __shared__ float s_phi[Ln];        // 4 KB
    __shared__ float s_red[RP][Vn];    // 3.75 KB
    __shared__ int   s_nmax;

    // ---- stage x row ----
    if (t < 128) ((float4*)s_x)[t] = ((const float4*)(x + (size_t)b * CELLn))[t];
    if (t == 128) s_nmax = 0;
    __syncthreads();

    // ---- params = exp(x@W.T + b); kappa = kappa_old + pre_kappa ----
    // Lane pair (2r, 2r+1) computes row r: each lane does half the dot
    // (64 float4 iterations instead of 128), combined via shfl_xor.
    if (t < 2 * 3 * Kn) {               // 180 lanes
        const int r = t >> 1;           // output row 0..89
        const int h = t & 1;            // which half of CELL
        const float4* wrow = (const float4*)(W + (size_t)r * CELLn) + h * (CELLn / 8);
        const float4* xr   = (const float4*)s_x + h * (CELLn / 8);
        float a0 = 0.f, a1 = 0.f, a2 = 0.f, a3 = 0.f;
        #pragma unroll 4
        for (int i = 0; i < CELLn / 8; ++i) {   // 64 iterations
            float4 wv = wrow[i];
            float4 xv = xr[i];
            a0 = fmaf(wv.x, xv.x, a0);
            a1 = fmaf(wv.y, xv.y, a1);
            a2 = fmaf(wv.z, xv.z, a2);
            a3 = fmaf(wv.w, xv.w, a3);
        }
        float part = (a0 + a1) + (a2 + a3);
        part += __shfl_xor(part, 1);    // pair lives in one wave (even,odd)
        if (h == 0) {
            float val = expf(part + bias[r]);
            if (r >= 2 * Kn) {          // pre_kappa -> kappa
                int k = r - 2 * Kn;
                float kap = kappa_old[(size_t)b * Kn + k] + val;
                s_abk[r] = kap;
                out_kappa[(size_t)b * Kn + k] = kap;
            } else {
                s_abk[r] = val;         // alpha or beta
            }
        }
    }
    __syncthreads();

    // ---- phi + effective window length (4 l-values per thread) ----
    const float scale = (float)Ln / text_lens[b];
    {
        const float fl0 = (float)t;
        const float fl1 = fl0 + 256.f;
        const float fl2 = fl0 + 512.f;
        const float fl3 = fl0 + 768.f;
        float p0 = 0.f, p1 = 0.f, p2 = 0.f, p3 = 0.f;
        #pragma unroll 2
        for (int k = 0; k < Kn; ++k) {
            const float a  = s_abk[k];
            const float bt = s_abk[Kn + k];
            const float kp = s_abk[2 * Kn + k];
            float d0 = kp - fl0, d1 = kp - fl1, d2 = kp - fl2, d3 = kp - fl3;
            p0 = fmaf(a, expf(-bt * d0 * d0), p0);
            p1 = fmaf(a, expf(-bt * d1 * d1), p1);
            p2 = fmaf(a, expf(-bt * d2 * d2), p2);
            p3 = fmaf(a, expf(-bt * d3 * d3), p3);
        }
        p0 *= scale; p1 *= scale; p2 *= scale; p3 *= scale;
        float* op = out_phi + (size_t)b * (Ln + 1);
        op[t]       = p0;
        op[t + 256] = p1;
        op[t + 512] = p2;
        op[t + 768] = p3;
        s_phi[t]       = p0;
        s_phi[t + 256] = p1;
        s_phi[t + 512] = p2;
        s_phi[t + 768] = p3;
        int nc = 0;
        if (p0 != 0.f) nc = t + 1;
        if (p1 != 0.f) nc = t + 257;
        if (p2 != 0.f) nc = t + 513;
        if (p3 != 0.f) nc = t + 769;
        if (nc) atomicMax(&s_nmax, nc);
        if (t == 0) {                   // l = Ln: out_phi only, not in stream
            float acc = 0.f;
            #pragma unroll 2
            for (int k = 0; k < Kn; ++k) {
                float d = s_abk[2 * Kn + k] - (float)Ln;
                acc = fmaf(s_abk[k], expf(-s_abk[Kn + k] * d * d), acc);
            }
            op[Ln] = acc * scale;
        }
    }
    __syncthreads();
    const int n_eff = s_nmax;  // rows beyond this have phi == 0.0f exactly

    // ---- w[v] = sum_{l<n_eff} phi[l] * onehots[b,l,v] ----
    if (t < RP * 20) {
        const int j  = t % 20;  // column quad: v = 4j..4j+3
        const int r0 = t / 20;  // row phase 0..11
        const f4v* oh = (const f4v*)(onehots + (size_t)b * Ln * Vn);
        f4v acc = {0.f, 0.f, 0.f, 0.f};
        #pragma unroll 2
        for (int l = r0; l < n_eff; l += RP) {
            f4v v = oh[l * 20 + j];   // 20-lane groups read 320B contiguous
            acc += s_phi[l] * v;
        }
        *((f4v*)&s_red[r0][j * 4]) = acc;
    }
    __syncthreads();

    if (t < Vn) {
        float s = 0.f;
        #pragma unroll
        for (int r = 0; r < RP; ++r) s += s_red[r][t];
        out_w[(size_t)b * Vn + t] = s;
    }
}

extern "C" void kernel_launch(void* const* d_in, const int* in_sizes, int n_in,
                              void* d_out, int out_size, void* d_ws, size_t ws_size,
                              hipStream_t stream) {
    const float* x         = (const float*)d_in[0];
    const float* kappa_old = (const float*)d_in[1];
    const float* onehots   = (const float*)d_in[2];
    const float* text_lens = (const float*)d_in[3];
    const float* W         = (const float*)d_in[4];
    const float* bias      = (const float*)d_in[5];

    float* out       = (float*)d_out;
    float* out_w     = out;                                  // [B, V]
    float* out_kappa = out + (size_t)Bn * Vn;                // [B, K]
    float* out_phi   = out_kappa + (size_t)Bn * Kn;          // [B, L+1]

    window_fused<<<Bn, NT, 0, stream>>>(x, kappa_old, onehots, text_lens, W, bias,
                                        out_w, out_kappa, out_phi);
}